// Round 8
// baseline (6076.097 us; speedup 1.0000x reference)
//
#include <hip/hip_runtime.h>
#include <hip/hip_fp16.h>

#define EMB 32
#define HID 256
#define TT  2048

typedef _Float16 half8_t __attribute__((ext_vector_type(8)));
typedef _Float16 half2_t __attribute__((ext_vector_type(2)));

// ---- single-CU-per-chain hybrid design (v8 = v7 + bias/4 fix) ----
// R0-R6 established: cross-block h-exchange costs V ~= 1900 cy (MALL
// visibility) per step, irreducible from HIP (6 variants) and unhideable
// (serial chain). So: eliminate the exchange. Full W = 576 KB > 512 KB
// regfile, but regs(432 KB) + LDS(147 KB) fits:
//   64 blocks (1 chain each) x 256 threads (4 waves, 1/SIMD, 512-reg budget)
//   thread (q = tid>>2, l = tid&3) owns units u = q + 64s (s=0..3),
//   gates r=0..3, col-slice 72l..72l+71 of [x(32); h(256)].
//   s=0..2 weights: 108 half8 in VGPRs; s=3 weights: 36 half8 in LDS.
//   Per step: 144 dot8, quad_reduce x16, activations, h -> LDS, 1 barrier.
// R7 post-mortem: accumulators are seeded from bias in EVERY lane and then
// quad_reduce SUMS the 4 lanes -> 4x bias (absmax 1.7e-1). Fix: prep stores
// bias*0.25; the quad tree-sum reconstructs bias exactly (exponent shifts
// and the 2-level pairwise sum are exact). Zero structural change.

// d_ws layout
#define REGW_SLOTS 108
#define LDSW_SLOTS 36
#define LDSW_OFF  (REGW_SLOTS * 256 * 16)            // 442368
#define BIAS_OFF  (LDSW_OFF + LDSW_SLOTS * 256 * 16) // 589824  (+4096)

// dynamic LDS layout
#define SM_WL    0
#define SM_BIAS  (LDSW_SLOTS * 256 * 16)   // 147456
#define SM_XH    (SM_BIAS + 4096)          // 151552  ([2][320] half)
#define SM_BYTES (SM_XH + 2 * 320 * 2 + 64)

__device__ __forceinline__ float fdot2(half2_t a, half2_t b, float c) {
#if __has_builtin(__builtin_amdgcn_fdot2)
    return __builtin_amdgcn_fdot2(a, b, c, false);
#else
    return c + (float)a[0] * (float)b[0] + (float)a[1] * (float)b[1];
#endif
}

__device__ __forceinline__ float dot8(half8_t w, half8_t x, float acc) {
    acc = fdot2(half2_t{w[0], w[1]}, half2_t{x[0], x[1]}, acc);
    acc = fdot2(half2_t{w[2], w[3]}, half2_t{x[2], x[3]}, acc);
    acc = fdot2(half2_t{w[4], w[5]}, half2_t{x[4], x[5]}, acc);
    acc = fdot2(half2_t{w[6], w[7]}, half2_t{x[6], x[7]}, acc);
    return acc;
}

__device__ __forceinline__ float rcp_fast(float v) {
#if __has_builtin(__builtin_amdgcn_rcpf)
    return __builtin_amdgcn_rcpf(v);
#else
    return 1.0f / v;
#endif
}
__device__ __forceinline__ float sigmoid_fast(float v) {
    return rcp_fast(1.0f + __expf(-v));
}
__device__ __forceinline__ float tanh_fast(float v) {
    v = fminf(fmaxf(v, -15.0f), 15.0f);
    float e = __expf(2.0f * v);
    return (e - 1.0f) * rcp_fast(e + 1.0f);
}

__device__ __forceinline__ float quad_reduce(float v) {
    int t = __builtin_amdgcn_mov_dpp(__float_as_int(v), 0xB1, 0xF, 0xF, true);
    v += __int_as_float(t);
    t = __builtin_amdgcn_mov_dpp(__float_as_int(v), 0x4E, 0xF, 0xF, true);
    v += __int_as_float(t);
    return v;
}

// ---- prep: repack W into REGW (per-thread slices) / LDSW / BIAS ----
// grid 145 x 256: 0..107 REGW slots; 108..143 LDSW slots; 144 bias
__global__ void prep_kernel(const float* __restrict__ W_ih,
                            const float* __restrict__ W_hh,
                            const float* __restrict__ b_ih,
                            const float* __restrict__ b_hh,
                            char* __restrict__ ws) {
    int bid = blockIdx.x, t = threadIdx.x, q = t >> 2, l = t & 3;
    if (bid < REGW_SLOTS + LDSW_SLOTS) {
        int k = bid;
        int r, jj, u;
        if (k < REGW_SLOTS) {
            int s = k / 36, m = k % 36;
            r = m / 9; jj = m % 9; u = q + 64 * s;
        } else {
            int m = k - REGW_SLOTS;
            r = m / 9; jj = m % 9; u = q + 192;
        }
        int row = r * HID + u;            // gates i,f,g,o = r 0..3
        half8_t v;
#pragma unroll
        for (int e = 0; e < 8; ++e) {
            int p = 72 * l + 8 * jj + e;  // col in [x(32); h(256)]
            float f = (p < EMB) ? W_ih[row * EMB + p]
                                : W_hh[row * HID + (p - EMB)];
            v[e] = (_Float16)f;
        }
        ((half8_t*)ws)[(size_t)k * 256 + t] = v;
    } else {
        if (t < 256) {
            float* bias = (float*)(ws + BIAS_OFF);
#pragma unroll
            for (int r = 0; r < 4; ++r)
                bias[t * 4 + r] = 0.25f * (b_ih[r * HID + t] + b_hh[r * HID + t]);
        }
    }
}

// ---- recurrent kernel: 64 blocks (1 chain each) x 256 threads ----
__global__ __launch_bounds__(256, 1) void rnn_kernel(const int* __restrict__ x,
                                                     const int* __restrict__ lengths,
                                                     const float* __restrict__ emb,
                                                     const char* __restrict__ ws,
                                                     float* __restrict__ out_) {
    extern __shared__ char smem[];
    half8_t*  WL = (half8_t*)(smem + SM_WL);
    float*    BL = (float*)(smem + SM_BIAS);
    _Float16* XH = (_Float16*)(smem + SM_XH);   // [2][320], cols: x 0..31, h 32..287

    const int b = blockIdx.x, tid = threadIdx.x;
    const int q = tid >> 2, l = tid & 3;

    // register-resident weights (statically indexed only — rule #20)
    half8_t w[REGW_SLOTS];
    {
        const half8_t* Wr = (const half8_t*)ws;
#pragma unroll
        for (int k = 0; k < REGW_SLOTS; ++k) w[k] = Wr[(size_t)k * 256 + tid];
    }
    // stage LDS weights + bias, zero xh buffers
    {
        const half8_t* Wg = (const half8_t*)(ws + LDSW_OFF);
        for (int m = tid; m < LDSW_SLOTS * 256; m += 256) WL[m] = Wg[m];
        const float* bg = (const float*)(ws + BIAS_OFF);
        for (int i = tid; i < 1024; i += 256) BL[i] = bg[i];
        for (int i = tid; i < 640; i += 256) XH[i] = (_Float16)0.0f;
    }
    int L = lengths[b];
    if (L > TT) L = TT;
    if (L < 1) L = 1;
    const int* __restrict__ xb = x + b * TT;
    __syncthreads();
    if (tid < EMB) XH[tid] = (_Float16)emb[xb[0] * EMB + tid];
    __syncthreads();

    float cs0 = 0.f, cs1 = 0.f, cs2 = 0.f, cs3 = 0.f;
    float hs0 = 0.f, hs1 = 0.f, hs2 = 0.f, hs3 = 0.f;

#pragma unroll 1
    for (int t = 0; t < L; ++t) {
        const _Float16* __restrict__ cur = XH + (t & 1) * 320;
        _Float16* __restrict__ nxt = XH + ((t + 1) & 1) * 320;

        // prefetch x(t+1) embedding (hidden under the dots)
        float ev = 0.f;
        if (tid < EMB) {
            int nt = (t + 1 < L) ? xb[t + 1] : 0;
            ev = emb[nt * EMB + tid];
        }

        // accumulators seeded with bias/4 per lane (quad-sum restores bias)
        float a[16];
#pragma unroll
        for (int s = 0; s < 4; ++s) {
            const float4 bb = *(const float4*)(BL + 4 * (q + 64 * s));
            a[4 * s + 0] = bb.x; a[4 * s + 1] = bb.y;
            a[4 * s + 2] = bb.z; a[4 * s + 3] = bb.w;
        }

        // 144 dot8: one xv per jj feeds 16 rows (4 u-slots x 4 gates)
#pragma unroll
        for (int jj = 0; jj < 9; ++jj) {
            const half8_t xv = *(const half8_t*)(cur + 72 * l + 8 * jj);
#pragma unroll
            for (int s = 0; s < 3; ++s)
#pragma unroll
                for (int r = 0; r < 4; ++r)
                    a[4 * s + r] = dot8(w[s * 36 + r * 9 + jj], xv, a[4 * s + r]);
#pragma unroll
            for (int r = 0; r < 4; ++r) {
                const half8_t wv = WL[(r * 9 + jj) * 256 + tid];  // lanes consecutive -> conflict-free
                a[12 + r] = dot8(wv, xv, a[12 + r]);
            }
        }

#pragma unroll
        for (int i = 0; i < 16; ++i) a[i] = quad_reduce(a[i]);

        // activations (all 4 lanes of a quad compute identically)
        {
            float iv = sigmoid_fast(a[0]),  fv = sigmoid_fast(a[1]);
            float gv = tanh_fast(a[2]),     ov = sigmoid_fast(a[3]);
            cs0 = fv * cs0 + iv * gv; hs0 = ov * tanh_fast(cs0);
        }
        {
            float iv = sigmoid_fast(a[4]),  fv = sigmoid_fast(a[5]);
            float gv = tanh_fast(a[6]),     ov = sigmoid_fast(a[7]);
            cs1 = fv * cs1 + iv * gv; hs1 = ov * tanh_fast(cs1);
        }
        {
            float iv = sigmoid_fast(a[8]),  fv = sigmoid_fast(a[9]);
            float gv = tanh_fast(a[10]),    ov = sigmoid_fast(a[11]);
            cs2 = fv * cs2 + iv * gv; hs2 = ov * tanh_fast(cs2);
        }
        {
            float iv = sigmoid_fast(a[12]), fv = sigmoid_fast(a[13]);
            float gv = tanh_fast(a[14]),    ov = sigmoid_fast(a[15]);
            cs3 = fv * cs3 + iv * gv; hs3 = ov * tanh_fast(cs3);
        }

        // publish h(t+1) and x(t+1) into the next buffer (LDS only)
        if (l == 0) {
            nxt[32 + q]       = (_Float16)hs0;
            nxt[32 + q + 64]  = (_Float16)hs1;
            nxt[32 + q + 128] = (_Float16)hs2;
            nxt[32 + q + 192] = (_Float16)hs3;
        }
        if (tid < EMB) nxt[tid] = (_Float16)ev;
        __syncthreads();
    }

    if (l == 0) {
        out_[(size_t)b * HID + q]       = hs0;
        out_[(size_t)b * HID + q + 64]  = hs1;
        out_[(size_t)b * HID + q + 128] = hs2;
        out_[(size_t)b * HID + q + 192] = hs3;
    }
}

extern "C" void kernel_launch(void* const* d_in, const int* in_sizes, int n_in,
                              void* d_out, int out_size, void* d_ws, size_t ws_size,
                              hipStream_t stream) {
    const int*   x       = (const int*)d_in[0];
    const int*   lengths = (const int*)d_in[1];
    const float* emb     = (const float*)d_in[2];
    const float* W_ih    = (const float*)d_in[3];
    const float* W_hh    = (const float*)d_in[4];
    const float* b_ih    = (const float*)d_in[5];
    const float* b_hh    = (const float*)d_in[6];

    static bool attr_done = false;
    if (!attr_done) {
        (void)hipFuncSetAttribute((const void*)rnn_kernel,
                                  hipFuncAttributeMaxDynamicSharedMemorySize,
                                  SM_BYTES);
        attr_done = true;
    }

    prep_kernel<<<145, 256, 0, stream>>>(W_ih, W_hh, b_ih, b_hh, (char*)d_ws);
    rnn_kernel<<<64, 256, SM_BYTES, stream>>>(x, lengths, emb,
                                              (const char*)d_ws, (float*)d_out);
}

// Round 9
// 2514.004 us; speedup vs baseline: 2.4169x; 2.4169x over previous
//
#include <hip/hip_runtime.h>
#include <hip/hip_fp16.h>

#define EMB 32
#define HID 256
#define BATCH 64
#define TT  2048

typedef _Float16 half8_t __attribute__((ext_vector_type(8)));
typedef _Float16 half2_t __attribute__((ext_vector_type(2)));

// ---- d_ws layout ----
// W    : [role 2][chunk 36][tid 512] half8   (589,824 B)
// BIAS : [Q 256][r 4] float
// ACK  : int[128]  (prep-inits to -1 every launch)
#define W_BYTES  (2*36*512*16)
#define BIAS_OFF W_BYTES                 // 589824
#define ACK_OFF  (BIAS_OFF + 4096)      // 593920

// ---- v10 design notes ----
// 2 blocks per chain (pair b, b^64), h exchanged through d_out with the
// tag protocol (slot k&1, tag (k>>1)&1 in bit0 of each half — consecutive
// writes to one slot carry OPPOSITE tags, so stale reads only retry).
// R2/R4/R5/R6 measured: every "fast path" variant (volatile, sc0, elected
// or geometric same-XCD pairing) is null-to-negative vs plain agent-scope
// polling -> v10 is PURE SLOW: one early poll overlapped with the own-h
// dots, then a hot agent-load spin (sleep only after 512 tries).
// R8 counters: launch_bounds(512,2) capped VGPRs at 128 -> the 144-reg
// weight set lived partly in AGPRs (VGPR_Count=100). (512,1) unlocks the
// 256-reg arch budget: weights become arch-resident, no accvgpr churn.
// (Only 128 blocks on 256 CUs -> the 2-blocks/CU cap never bought anything.)
// emb prefetch is 2-deep: ev for step t+1 is loaded at step t-1, so even an
// HBM miss (~900cy; emb 4MB > per-XCD L2) never blocks barrier A.

__device__ __forceinline__ float fdot2(half2_t a, half2_t b, float c) {
#if __has_builtin(__builtin_amdgcn_fdot2)
    return __builtin_amdgcn_fdot2(a, b, c, false);
#else
    return c + (float)a[0] * (float)b[0] + (float)a[1] * (float)b[1];
#endif
}

__device__ __forceinline__ float dot8(half8_t w, half8_t x, float acc) {
    acc = fdot2(half2_t{w[0], w[1]}, half2_t{x[0], x[1]}, acc);
    acc = fdot2(half2_t{w[2], w[3]}, half2_t{x[2], x[3]}, acc);
    acc = fdot2(half2_t{w[4], w[5]}, half2_t{x[4], x[5]}, acc);
    acc = fdot2(half2_t{w[6], w[7]}, half2_t{x[6], x[7]}, acc);
    return acc;
}

__device__ __forceinline__ float rcp_fast(float v) {
#if __has_builtin(__builtin_amdgcn_rcpf)
    return __builtin_amdgcn_rcpf(v);
#else
    return 1.0f / v;
#endif
}
__device__ __forceinline__ float sigmoid_fast(float v) {
    return rcp_fast(1.0f + __expf(-v));
}
__device__ __forceinline__ float tanh_fast(float v) {
    v = fminf(fmaxf(v, -15.0f), 15.0f);
    float e = __expf(2.0f * v);
    return (e - 1.0f) * rcp_fast(e + 1.0f);
}

// LDS-only barrier: no vmcnt drain — publish stores / polls stay in flight.
__device__ __forceinline__ void barrier_lds() {
    asm volatile("s_waitcnt lgkmcnt(0)\n\ts_barrier" ::: "memory");
}

__device__ __forceinline__ float quad_reduce(float v) {
    int t = __builtin_amdgcn_mov_dpp(__float_as_int(v), 0xB1, 0xF, 0xF, true);
    v += __int_as_float(t);
    t = __builtin_amdgcn_mov_dpp(__float_as_int(v), 0x4E, 0xF, 0xF, true);
    v += __int_as_float(t);
    return v;
}

__device__ __forceinline__ unsigned int load_slow(const unsigned int* p) {
    return __hip_atomic_load(p, __ATOMIC_RELAXED, __HIP_MEMORY_SCOPE_AGENT);
}

__device__ __forceinline__ int gate_row(int r, int Q) {
    return r == 0 ? Q : r == 1 ? 256 + Q : r == 2 ? 512 + Q : 768 + Q;
}

// ---- prep: weights/bias + SLOW (d_out) tag init + ACK init ----
// grid 105 x 512: 0..71 weights; 72 bias+ack; 73..104 SLOW tags
__global__ void prep_kernel(const float* __restrict__ W_ih,
                            const float* __restrict__ W_hh,
                            const float* __restrict__ b_ih,
                            const float* __restrict__ b_hh,
                            char* __restrict__ ws,
                            unsigned int* __restrict__ outw) {
    int bid = blockIdx.x, t = threadIdx.x;
    if (bid < 72) {
        int R = bid / 36, c = bid % 36;
        int r = c / 9, jj = c % 9;
        int Q = 128 * R + (t >> 2), l = t & 3;
        int row = gate_row(r, Q);
        half8_t v;
#pragma unroll
        for (int e = 0; e < 8; ++e) {
            int p = 8 * jj + e;
            float f;
            if (p < 8)       f = W_ih[row * EMB + 8 * l + p];
            else if (p < 40) f = W_hh[row * HID + 128 * R + 32 * l + (p - 8)];
            else             f = W_hh[row * HID + 128 * (1 - R) + 32 * l + (p - 40)];
            v[e] = (_Float16)f;
        }
        ((half8_t*)ws)[((size_t)bid) * 512 + t] = v;
    } else if (bid == 72) {
        float* bias = (float*)(ws + BIAS_OFF);
        for (int i = t; i < 1024; i += 512) {
            int Q = i >> 2, r = i & 3;
            int row = gate_row(r, Q);
            bias[i] = b_ih[row] + b_hh[row];
        }
        if (t < 128) ((int*)(ws + ACK_OFF))[t] = -1;
    } else {
        int g = (bid - 73) * 512 + t;                  // SLOW tags in d_out
        outw[g] = ((g >> 6) & 1) ? 0x00010001u : 0u;
    }
}

// ---- recurrent kernel: 128 blocks (2 per chain), 512 threads ----
__global__ __launch_bounds__(512, 1) void rnn_kernel(const int* __restrict__ x,
                                                     const int* __restrict__ lengths,
                                                     const float* __restrict__ emb,
                                                     char* __restrict__ ws,
                                                     float* __restrict__ out_) {
    __shared__ __align__(16) _Float16 xhbuf[2][320];

    const int bid  = blockIdx.x;
    const int role = bid >> 6;
    const int b    = bid & 63;
    const int pbid = bid ^ 64;
    const int tid  = threadIdx.x;
    const int q    = tid >> 2;
    const int l    = tid & 3;
    const int Q    = 128 * role + q;

    half8_t w[4][9];
    {
        const half8_t* Wp = (const half8_t*)ws + (size_t)role * 36 * 512;
#pragma unroll
        for (int r = 0; r < 4; ++r)
#pragma unroll
            for (int jj = 0; jj < 9; ++jj) w[r][jj] = Wp[(r * 9 + jj) * 512 + tid];
    }
    float4 bs = *(const float4*)(ws + BIAS_OFF + (size_t)Q * 16);

    unsigned int* sexch = (unsigned int*)out_ + (size_t)b * 256;  // exchange (MALL)
    unsigned int* smine = sexch + role * 128;
    unsigned int* spart = sexch + (1 - role) * 128;

    int L = lengths[b];
    if (L > TT) L = TT;
    if (L < 1) L = 1;
    const int* __restrict__ xb = x + b * TT;

    if (tid < 320) xhbuf[0][tid] = (_Float16)0.0f;
    __syncthreads();
    if (tid < EMB) {
        float e0 = emb[xb[0] * EMB + tid];
        xhbuf[0][72 * (tid >> 3) + (tid & 7)] = (_Float16)e0;
    }
    __syncthreads();

    float cc = 0.0f, hh = 0.0f;

    // prologue: own+x partials for step 0
    float p0 = 0.f, p1 = 0.f, p2 = 0.f, p3 = 0.f;
    {
        const _Float16* cur = xhbuf[0];
        half8_t xv[5];
#pragma unroll
        for (int jj = 0; jj < 5; ++jj) xv[jj] = *(const half8_t*)(cur + 72 * l + 8 * jj);
#pragma unroll
        for (int jj = 0; jj < 5; ++jj) {
            p0 = dot8(w[0][jj], xv[jj], p0);
            p1 = dot8(w[1][jj], xv[jj], p1);
            p2 = dot8(w[2][jj], xv[jj], p2);
            p3 = dot8(w[3][jj], xv[jj], p3);
        }
    }

    // 2-deep emb pipeline: ev holds the embedding for step t+1
    float ev = 0.f;
    if (tid >= 64 && tid < 64 + EMB) {
        int nt = (1 < L) ? xb[1] : 0;
        ev = emb[nt * EMB + (tid - 64)];
    }

#pragma unroll 1
    for (int t = 0; t < L; ++t) {
        const _Float16* __restrict__ cur = xhbuf[t & 1];
        _Float16* __restrict__ nxt = xhbuf[(t + 1) & 1];

        // issue the t+2 embedding load now; consumed next iteration
        float ev2 = 0.0f;
        if (tid >= 64 && tid < 64 + EMB) {
            int nt2 = (t + 2 < L) ? xb[t + 2] : 0;
            ev2 = emb[nt2 * EMB + (tid - 64)];
        }

        // 1. partner-col dots (jj 5..8) finish the gate pre-activations
        float a0 = p0, a1 = p1, a2 = p2, a3 = p3;
        {
            half8_t xv[4];
#pragma unroll
            for (int jj = 0; jj < 4; ++jj)
                xv[jj] = *(const half8_t*)(cur + 72 * l + 40 + 8 * jj);
#pragma unroll
            for (int jj = 0; jj < 4; ++jj) {
                a0 = dot8(w[0][5 + jj], xv[jj], a0);
                a1 = dot8(w[1][5 + jj], xv[jj], a1);
                a2 = dot8(w[2][5 + jj], xv[jj], a2);
                a3 = dot8(w[3][5 + jj], xv[jj], a3);
            }
        }

        // 2. reduce + activations
        a0 = quad_reduce(a0);
        a1 = quad_reduce(a1);
        a2 = quad_reduce(a2);
        a3 = quad_reduce(a3);
        float iv = sigmoid_fast(a0 + bs.x);
        float fv = sigmoid_fast(a1 + bs.y);
        float gv = tanh_fast(a2 + bs.z);
        float ov = sigmoid_fast(a3 + bs.w);
        cc = fv * cc + iv * gv;
        hh = ov * tanh_fast(cc);

        const unsigned int tg = ((unsigned)(t + 1) >> 1) & 1u;
        const int ps_ = (t + 1) & 1;

        // 3. publish own h(t+1) (agent store -> MALL; tag in bit0 per half)
        _Float16 hf = (_Float16)hh;
        unsigned short hb = __builtin_bit_cast(unsigned short, hf);
        unsigned int tb = (unsigned int)((hb & 0xFFFEu) | tg);
        unsigned int nb = (unsigned int)__builtin_amdgcn_mov_dpp((int)tb, 0x104, 0xF, 0xF, true);
        if ((tid & 7) == 0) {
            unsigned int dwv = tb | (nb << 16);
            int o = ps_ * 64 + (tid >> 3);
            __hip_atomic_store(smine + o, dwv, __ATOMIC_RELAXED, __HIP_MEMORY_SCOPE_AGENT);
        }

        // 4. own-h(t+1) and x(t+1) into next buffer
        if (l == 0) nxt[72 * (q >> 5) + 8 + (q & 31)] = hf;
        if (tid >= 64 && tid < 64 + EMB) {
            int k = tid - 64;
            nxt[72 * (k >> 3) + (k & 7)] = (_Float16)ev;
        }
        barrier_lds();   // A

        // 5. issue first partner poll early, then own+x dots in its shadow
        unsigned int fdw = 0;
        const unsigned int* sp = spart + ps_ * 64 + tid;
        if (tid < 64) fdw = load_slow(sp);

        p0 = 0.f; p1 = 0.f; p2 = 0.f; p3 = 0.f;
        {
            half8_t xv[5];
#pragma unroll
            for (int jj = 0; jj < 5; ++jj)
                xv[jj] = *(const half8_t*)(nxt + 72 * l + 8 * jj);
#pragma unroll
            for (int jj = 0; jj < 5; ++jj) {
                p0 = dot8(w[0][jj], xv[jj], p0);
                p1 = dot8(w[1][jj], xv[jj], p1);
                p2 = dot8(w[2][jj], xv[jj], p2);
                p3 = dot8(w[3][jj], xv[jj], p3);
            }
        }

        // 6. wave0: finish the spin (pure agent polling; stale reads only retry)
        if (tid < 64) {
            unsigned int dw = fdw;
            int tries = 0;
            while (!__all(((dw & 1u) == tg) && (((dw >> 16) & 1u) == tg))) {
                if (++tries > (1 << 20)) break;
                if (tries > 512) __builtin_amdgcn_s_sleep(2);
                dw = load_slow(sp);
            }
            unsigned short h0 = (unsigned short)(dw & 0xFFFEu);
            unsigned short h1 = (unsigned short)((dw >> 16) & 0xFFFEu);
            int j0 = 2 * tid, j1 = 2 * tid + 1;
            nxt[72 * (j0 >> 5) + 40 + (j0 & 31)] = __builtin_bit_cast(_Float16, h0);
            nxt[72 * (j1 >> 5) + 40 + (j1 & 31)] = __builtin_bit_cast(_Float16, h1);
        }
        barrier_lds();   // B

        ev = ev2;
    }

    // end handshake: partner done reading my d_out region -> safe to overwrite
    int* ack = (int*)(ws + ACK_OFF);
    if (tid == 0)
        __hip_atomic_store(&ack[bid], L, __ATOMIC_RELEASE, __HIP_MEMORY_SCOPE_AGENT);
    if (tid == 0) {
        int tries = 0;
        while (__hip_atomic_load(&ack[pbid], __ATOMIC_ACQUIRE, __HIP_MEMORY_SCOPE_AGENT) != L) {
            if (++tries > (1 << 20)) break;
            __builtin_amdgcn_s_sleep(8);
        }
    }
    __syncthreads();
    if (l == 0) out_[(size_t)b * 256 + 128 * role + q] = hh;
}

extern "C" void kernel_launch(void* const* d_in, const int* in_sizes, int n_in,
                              void* d_out, int out_size, void* d_ws, size_t ws_size,
                              hipStream_t stream) {
    const int*   x       = (const int*)d_in[0];
    const int*   lengths = (const int*)d_in[1];
    const float* emb     = (const float*)d_in[2];
    const float* W_ih    = (const float*)d_in[3];
    const float* W_hh    = (const float*)d_in[4];
    const float* b_ih    = (const float*)d_in[5];
    const float* b_hh    = (const float*)d_in[6];

    prep_kernel<<<105, 512, 0, stream>>>(W_ih, W_hh, b_ih, b_hh,
                                         (char*)d_ws, (unsigned int*)d_out);
    rnn_kernel<<<128, 512, 0, stream>>>(x, lengths, emb, (char*)d_ws, (float*)d_out);
}